// Round 2
// baseline (459.543 us; speedup 1.0000x reference)
//
#include <hip/hip_runtime.h>
#include <math.h>

#define Bn 2048
#define Sn 277
#define Rn 80
#define Ln 12
#define Zn 56
#define NROWS (Bn * Sn)                   // 567296
#define ROWS_PER_BLK 64
#define NBLK_BCE (NROWS / ROWS_PER_BLK)   // 8864 exactly
#define NMOM 8
#define NBLK_TOT (NBLK_BCE + NMOM)

// ws layout (bytes):
//   [0,      192)   u32 sbits_g[12*4]     (setup kernel, stride-4 per lhs)
//   [192,    512)   int lhs_g[80]
//   [512,  71424)   double bce_partial[8864]
//   [71424,171776)  float var_partial[8][3136]
//   [171776,173568) float avg_partial[8][56]
#define WS_SBITS 0
#define WS_LHS   192
#define WS_BCE   512
#define WS_VAR   71424
#define WS_AVG   171776

__global__ __launch_bounds__(128) void setup_kernel(
    const float* __restrict__ masks, const int* __restrict__ lhs, char* __restrict__ ws)
{
    unsigned* sbits_g = (unsigned*)(ws + WS_SBITS);
    int* lhs_g = (int*)(ws + WS_LHS);
    const int t = threadIdx.x;
    if (t < Ln * 4) {
        const int l = t >> 2, w = t & 3;
        unsigned bits = 0u;
        if (w < 3) {
            for (int b = 0; b < 32; ++b) {
                const int j = w * 32 + b;
                if (j < Rn && masks[l * Rn + j] > 0.5f) bits |= (1u << b);
            }
        }
        sbits_g[t] = bits;
    }
    if (t >= 48 && t < 48 + Rn) lhs_g[t - 48] = lhs[t - 48];
}

__global__ __launch_bounds__(256) void main_kernel(
    const float* __restrict__ x, const float* __restrict__ recon,
    const float* __restrict__ mu, char* __restrict__ ws)
{
    const int tid = threadIdx.x;

    if (blockIdx.x < NBLK_BCE) {
        // ---------------- BCE part: 16 lanes per row, 64 rows per block ----
        const unsigned* sbits_g = (const unsigned*)(ws + WS_SBITS);
        const int* lhs_g = (const int*)(ws + WS_LHS);
        double* bce_partial = (double*)(ws + WS_BCE);

        __shared__ unsigned sbits[Ln * 4];
        __shared__ int slhs[Rn];
        __shared__ float swsum[4];

        if (tid < Ln * 4) sbits[tid] = sbits_g[tid];
        else if (tid >= 64 && tid < 64 + Rn) slhs[tid - 64] = lhs_g[tid - 64];
        __syncthreads();

        const int grp = tid >> 4;        // 16 row-groups per block
        const int sl  = tid & 15;        // lane within group
        float contrib = 0.0f;

        for (int it = 0; it < 4; ++it) {
            const int row = blockIdx.x * ROWS_PER_BLK + it * 16 + grp;
            const float4* xp = (const float4*)(x + (size_t)row * Rn);
            const float4* rp = (const float4*)(recon + (size_t)row * Rn);

            // main chunk (elements 4*sl .. 4*sl+3) + extra chunk (64+4*sl..) for sl<4
            float4 xv = xp[sl];
            float4 rv = rp[sl];
            float4 xe = make_float4(0.f, 0.f, 0.f, 0.f);
            float4 re = make_float4(0.f, 0.f, 0.f, 0.f);
            if (sl < 4) { xe = xp[16 + sl]; re = rp[16 + sl]; }

            // argmax of the one-hot row (value 1.0 exactly at the true rule)
            const int jb = 4 * sl;          // 0..60
            const int je = 64 + 4 * sl;     // 64..79 valid only for sl<4 (else >79, never matches)
            int cand = -1;
            if (xv.x > 0.5f) cand = jb;
            if (xv.y > 0.5f) cand = jb + 1;
            if (xv.z > 0.5f) cand = jb + 2;
            if (xv.w > 0.5f) cand = jb + 3;
            if (xe.x > 0.5f) cand = je;
            if (xe.y > 0.5f) cand = je + 1;
            if (xe.z > 0.5f) cand = je + 2;
            if (xe.w > 0.5f) cand = je + 3;
            cand = max(cand, __shfl_xor(cand, 1));
            cand = max(cand, __shfl_xor(cand, 2));
            cand = max(cand, __shfl_xor(cand, 4));
            cand = max(cand, __shfl_xor(cand, 8));
            const int amax = cand;

            const int l = slhs[amax];                 // same addr across group -> LDS broadcast
            const unsigned bw = sbits[l * 4 + (sl >> 3)];   // word holding bits 4sl..4sl+3
            const unsigned b2 = sbits[l * 4 + 2];           // word holding extra-chunk bits
            const int sh = 4 * (sl & 7);

            const float v0 = ((bw >> (sh + 0)) & 1u) ? rv.x : 0.f;
            const float v1 = ((bw >> (sh + 1)) & 1u) ? rv.y : 0.f;
            const float v2 = ((bw >> (sh + 2)) & 1u) ? rv.z : 0.f;
            const float v3 = ((bw >> (sh + 3)) & 1u) ? rv.w : 0.f;
            const float e0 = ((b2 >> (sh + 0)) & 1u) ? re.x : 0.f;
            const float e1 = ((b2 >> (sh + 1)) & 1u) ? re.y : 0.f;
            const float e2 = ((b2 >> (sh + 2)) & 1u) ? re.z : 0.f;
            const float e3 = ((b2 >> (sh + 3)) & 1u) ? re.w : 0.f;

            float d = ((v0 + v1) + (v2 + v3)) + ((e0 + e1) + (e2 + e3));
            d += __shfl_xor(d, 1);
            d += __shfl_xor(d, 2);
            d += __shfl_xor(d, 4);
            d += __shfl_xor(d, 8);
            const float invd = 1.0f / d;

            float ta = -1.0f;   // sentinel: this lane doesn't own amax
            float ss = 0.0f;
            {
                float t;
                t = fminf(v0 * invd, 1.f); ss += fmaxf(__logf(1.f - t), -100.f); if (jb + 0 == amax) ta = t;
                t = fminf(v1 * invd, 1.f); ss += fmaxf(__logf(1.f - t), -100.f); if (jb + 1 == amax) ta = t;
                t = fminf(v2 * invd, 1.f); ss += fmaxf(__logf(1.f - t), -100.f); if (jb + 2 == amax) ta = t;
                t = fminf(v3 * invd, 1.f); ss += fmaxf(__logf(1.f - t), -100.f); if (jb + 3 == amax) ta = t;
                t = fminf(e0 * invd, 1.f); ss += fmaxf(__logf(1.f - t), -100.f); if (je + 0 == amax) ta = t;
                t = fminf(e1 * invd, 1.f); ss += fmaxf(__logf(1.f - t), -100.f); if (je + 1 == amax) ta = t;
                t = fminf(e2 * invd, 1.f); ss += fmaxf(__logf(1.f - t), -100.f); if (je + 2 == amax) ta = t;
                t = fminf(e3 * invd, 1.f); ss += fmaxf(__logf(1.f - t), -100.f); if (je + 3 == amax) ta = t;
            }
            // owner lane: replace log1p(-t_amax) with log(t_amax)
            if (ta >= 0.0f)
                ss += fmaxf(__logf(ta), -100.f) - fmaxf(__logf(1.f - ta), -100.f);
            contrib += ss;
        }

        #pragma unroll
        for (int m = 32; m; m >>= 1) contrib += __shfl_xor(contrib, m);
        if ((tid & 63) == 0) swsum[tid >> 6] = contrib;
        __syncthreads();
        if (tid == 0)
            bce_partial[blockIdx.x] = (double)((swsum[0] + swsum[1]) + (swsum[2] + swsum[3]));
    } else {
        // ---------------- moment part: 8 blocks x 256 mu-rows ----------------
        float* var_partial = (float*)(ws + WS_VAR);
        float* avg_partial = (float*)(ws + WS_AVG);
        __shared__ float sm[64 * Zn];   // 14336 B

        const int m = blockIdx.x - NBLK_BCE;   // 0..7
        float acc[13];
        #pragma unroll
        for (int k = 0; k < 13; ++k) acc[k] = 0.0f;
        float asum = 0.0f;

        for (int c = 0; c < 4; ++c) {
            __syncthreads();
            const float* src = mu + ((size_t)m * 256 + c * 64) * Zn;
            for (int i = tid; i < 64 * Zn; i += 256) sm[i] = src[i];
            __syncthreads();

            #pragma unroll
            for (int k = 0; k < 13; ++k) {
                const int p = tid + 256 * k;
                if (p < Zn * Zn) {
                    const int i = p / Zn, j = p - i * Zn;
                    float a = 0.0f;
                    #pragma unroll 8
                    for (int r = 0; r < 64; ++r) a = fmaf(sm[r * Zn + i], sm[r * Zn + j], a);
                    acc[k] += a;
                }
            }
            if (tid < Zn) {
                float s = 0.0f;
                #pragma unroll 8
                for (int r = 0; r < 64; ++r) s += sm[r * Zn + tid];
                asum += s;
            }
        }
        #pragma unroll
        for (int k = 0; k < 13; ++k) {
            const int p = tid + 256 * k;
            if (p < Zn * Zn) var_partial[m * (Zn * Zn) + p] = acc[k];
        }
        if (tid < Zn) avg_partial[m * Zn + tid] = asum;
    }
}

__global__ __launch_bounds__(256) void finalize_kernel(
    const char* __restrict__ ws, float* __restrict__ out)
{
    const double* bce_partial = (const double*)(ws + WS_BCE);
    const float* var_partial = (const float*)(ws + WS_VAR);
    const float* avg_partial = (const float*)(ws + WS_AVG);
    __shared__ double sb[4];
    __shared__ float sv[4], sa[4];
    const int tid = threadIdx.x;

    double bsum = 0.0;
    for (int i = tid; i < NBLK_BCE; i += 256) bsum += bce_partial[i];

    float vsum = 0.0f;
    for (int p = tid; p < Zn * Zn; p += 256) {
        float v = 0.0f;
        #pragma unroll
        for (int m = 0; m < NMOM; ++m) v += var_partial[m * (Zn * Zn) + p];
        const int i = p / Zn, j = p - i * Zn;
        const float e = v * (1.0f / (float)Bn) - ((i == j) ? 1.0f : 0.0f);
        vsum += fabsf(e);
    }

    float asum = 0.0f;
    for (int z = tid; z < Zn; z += 256) {
        float a = 0.0f;
        #pragma unroll
        for (int m = 0; m < NMOM; ++m) a += avg_partial[m * Zn + z];
        asum += a * a;
    }

    #pragma unroll
    for (int o = 32; o; o >>= 1) {
        bsum += __shfl_down(bsum, o, 64);
        vsum += __shfl_down(vsum, o, 64);
        asum += __shfl_down(asum, o, 64);
    }
    if ((tid & 63) == 0) { const int w = tid >> 6; sb[w] = bsum; sv[w] = vsum; sa[w] = asum; }
    __syncthreads();
    if (tid == 0) {
        const double tb = (sb[0] + sb[1]) + (sb[2] + sb[3]);
        const double tv = (double)((sv[0] + sv[1]) + (sv[2] + sv[3]));
        const double ta = (double)((sa[0] + sa[1]) + (sa[2] + sa[3]));
        const double bce = -tb / ((double)Sn * (double)Bn);
        const double mom = ta / ((double)Bn * (double)Bn * (double)Zn)
                         + tv / ((double)Zn * (double)Zn);
        out[0] = (float)(bce + mom);
    }
}

extern "C" void kernel_launch(void* const* d_in, const int* in_sizes, int n_in,
                              void* d_out, int out_size, void* d_ws, size_t ws_size,
                              hipStream_t stream)
{
    const float* x     = (const float*)d_in[0];
    const float* recon = (const float*)d_in[1];
    const float* mu    = (const float*)d_in[2];
    // d_in[3] = log_var: unused by the reference
    const float* masks = (const float*)d_in[4];
    const int*   lhs   = (const int*)d_in[5];
    float* out = (float*)d_out;
    char* ws = (char*)d_ws;

    setup_kernel<<<1, 128, 0, stream>>>(masks, lhs, ws);
    main_kernel<<<NBLK_TOT, 256, 0, stream>>>(x, recon, mu, ws);
    finalize_kernel<<<1, 256, 0, stream>>>(ws, out);
}

// Round 3
// 383.185 us; speedup vs baseline: 1.1993x; 1.1993x over previous
//
#include <hip/hip_runtime.h>
#include <math.h>

#define Bn 2048
#define Sn 277
#define Rn 80
#define Ln 12
#define Zn 56
#define NROWS (Bn * Sn)                   // 567296
#define ROWS_PER_BLK 64
#define NBLK_BCE (NROWS / ROWS_PER_BLK)   // 8864 exactly
#define NMOM 8
#define NBLK_TOT (NBLK_BCE + NMOM)

// ws layout (bytes):
//   [0,     1280)   u32 cmask_g[80*4]   per-rule combined mask bits (setup kernel)
//   [1280, 72192)   double bce_partial[8864]
//   [72192,172544)  float var_partial[8][3136]
//   [172544,174336) float avg_partial[8][56]
#define WS_CMASK 0
#define WS_BCE   1280
#define WS_VAR   72192
#define WS_AVG   172544

__global__ __launch_bounds__(256) void setup_kernel(
    const float* __restrict__ masks, const int* __restrict__ lhs, char* __restrict__ ws)
{
    unsigned* cmask_g = (unsigned*)(ws + WS_CMASK);
    for (int idx = threadIdx.x; idx < Rn * 4; idx += 256) {
        const int r = idx >> 2, w = idx & 3;
        unsigned bits = 0u;
        if (w < 3) {
            const int l = lhs[r];
            for (int b = 0; b < 32; ++b) {
                const int j = w * 32 + b;
                if (j < Rn && masks[l * Rn + j] > 0.5f) bits |= (1u << b);
            }
        }
        cmask_g[idx] = bits;
    }
}

__global__ __launch_bounds__(256) void main_kernel(
    const float* __restrict__ x, const float* __restrict__ recon,
    const float* __restrict__ mu, char* __restrict__ ws)
{
    const int tid = threadIdx.x;

    if (blockIdx.x >= NMOM) {
        // ---------------- BCE: 64 rows per block ----------------
        const int bid = blockIdx.x - NMOM;
        __shared__ unsigned scmask[Rn * 4];   // 1280 B
        __shared__ int samax[ROWS_PER_BLK];   // 256 B
        __shared__ float swsum[4];

        const unsigned* cmask_g = (const unsigned*)(ws + WS_CMASK);
        double* bce_partial = (double*)(ws + WS_BCE);

        scmask[tid] = cmask_g[tid];
        if (tid < Rn * 4 - 256) scmask[256 + tid] = cmask_g[256 + tid];

        // Phase 1: fully-coalesced scan of this block's x slab (64 rows = 1280 float4).
        const float4* xp = (const float4*)x + (size_t)bid * 1280;
        float4 x0 = xp[tid];
        float4 x1 = xp[tid + 256];
        float4 x2 = xp[tid + 512];
        float4 x3 = xp[tid + 768];
        float4 x4 = xp[tid + 1024];

        auto detect = [&](float4 v, int p) {
            int comp = -1;
            if (v.x > 0.5f) comp = 0;
            if (v.y > 0.5f) comp = 1;
            if (v.z > 0.5f) comp = 2;
            if (v.w > 0.5f) comp = 3;
            if (comp >= 0) {
                const int row = p / 20;          // local row 0..63
                const int f = p - row * 20;      // float4 within row
                samax[row] = f * 4 + comp;       // exactly one writer per row
            }
        };
        detect(x0, tid);
        detect(x1, tid + 256);
        detect(x2, tid + 512);
        detect(x3, tid + 768);
        detect(x4, tid + 1024);
        __syncthreads();

        // Phase 2: 4 lanes per row; lane c owns float4s c, c+4, c+8, c+12, c+16.
        const int lrow = tid >> 2, c = tid & 3;
        const size_t row = (size_t)bid * ROWS_PER_BLK + lrow;
        const float4* rp = (const float4*)(recon + row * Rn);
        float4 m0 = rp[c];
        float4 m1 = rp[c + 4];
        float4 m2 = rp[c + 8];
        float4 m3 = rp[c + 12];
        float4 m4 = rp[c + 16];

        const int amax = samax[lrow];
        const unsigned u0 = scmask[amax * 4 + 0];
        const unsigned u1 = scmask[amax * 4 + 1];
        const unsigned u2 = scmask[amax * 4 + 2];
        const int sh = 4 * c;

        auto msk = [&](float4& v, unsigned u, int s) {
            v.x = ((u >> (s + 0)) & 1u) ? v.x : 0.f;
            v.y = ((u >> (s + 1)) & 1u) ? v.y : 0.f;
            v.z = ((u >> (s + 2)) & 1u) ? v.z : 0.f;
            v.w = ((u >> (s + 3)) & 1u) ? v.w : 0.f;
        };
        msk(m0, u0, sh);      // elems 4c      .. +3   (k=0)
        msk(m1, u0, sh + 16); // elems 4c+16   .. +3   (k=1)
        msk(m2, u1, sh);      // elems 4c+32            (k=2)
        msk(m3, u1, sh + 16); // elems 4c+48            (k=3)
        msk(m4, u2, sh);      // elems 4c+64            (k=4)

        float d = ((m0.x + m0.y) + (m0.z + m0.w))
                + ((m1.x + m1.y) + (m1.z + m1.w))
                + ((m2.x + m2.y) + (m2.z + m2.w))
                + ((m3.x + m3.y) + (m3.z + m3.w))
                + ((m4.x + m4.y) + (m4.z + m4.w));
        d += __shfl_xor(d, 1);
        d += __shfl_xor(d, 2);
        const float invd = 1.0f / d;

        const int fa = amax >> 2;        // owning float4 0..19
        const int ca = fa & 3;           // owning lane
        const int ka = fa >> 2;          // owning chunk
        const int comp = amax & 3;
        const bool owner = (c == ca);

        float ss = 0.0f;
        float ta = 1.0f;
        auto acc = [&](float4 v, int k) {
            const float t0 = fminf(v.x * invd, 1.f);
            const float t1 = fminf(v.y * invd, 1.f);
            const float t2 = fminf(v.z * invd, 1.f);
            const float t3 = fminf(v.w * invd, 1.f);
            ss += fmaxf(__logf(1.f - t0), -100.f);
            ss += fmaxf(__logf(1.f - t1), -100.f);
            ss += fmaxf(__logf(1.f - t2), -100.f);
            ss += fmaxf(__logf(1.f - t3), -100.f);
            if (owner && k == ka)
                ta = (comp == 0) ? t0 : (comp == 1) ? t1 : (comp == 2) ? t2 : t3;
        };
        acc(m0, 0); acc(m1, 1); acc(m2, 2); acc(m3, 3); acc(m4, 4);
        if (owner)
            ss += fmaxf(__logf(ta), -100.f) - fmaxf(__logf(1.f - ta), -100.f);

        // Block reduction -> one double per block.
        float contrib = ss;
        #pragma unroll
        for (int o = 32; o; o >>= 1) contrib += __shfl_xor(contrib, o);
        if ((tid & 63) == 0) swsum[tid >> 6] = contrib;
        __syncthreads();
        if (tid == 0)
            bce_partial[bid] = (double)((swsum[0] + swsum[1]) + (swsum[2] + swsum[3]));
    } else {
        // ---------------- moments: 8 blocks x 256 mu-rows, 32-row LDS chunks ----
        float* var_partial = (float*)(ws + WS_VAR);
        float* avg_partial = (float*)(ws + WS_AVG);
        __shared__ float sm[32 * Zn];   // 7168 B

        const int m = blockIdx.x;   // 0..7
        float acc[13];
        #pragma unroll
        for (int k = 0; k < 13; ++k) acc[k] = 0.0f;
        float asum = 0.0f;

        for (int ch = 0; ch < 8; ++ch) {
            __syncthreads();
            const float* src = mu + ((size_t)m * 256 + ch * 32) * Zn;
            #pragma unroll
            for (int i = 0; i < 7; ++i) sm[tid + 256 * i] = src[tid + 256 * i];
            __syncthreads();

            #pragma unroll
            for (int k = 0; k < 13; ++k) {
                const int p = tid + 256 * k;
                if (p < Zn * Zn) {
                    const int i = p / Zn, j = p - i * Zn;
                    float a = 0.0f;
                    #pragma unroll 8
                    for (int r = 0; r < 32; ++r) a = fmaf(sm[r * Zn + i], sm[r * Zn + j], a);
                    acc[k] += a;
                }
            }
            if (tid < Zn) {
                float s = 0.0f;
                #pragma unroll 8
                for (int r = 0; r < 32; ++r) s += sm[r * Zn + tid];
                asum += s;
            }
        }
        #pragma unroll
        for (int k = 0; k < 13; ++k) {
            const int p = tid + 256 * k;
            if (p < Zn * Zn) var_partial[m * (Zn * Zn) + p] = acc[k];
        }
        if (tid < Zn) avg_partial[m * Zn + tid] = asum;
    }
}

__global__ __launch_bounds__(256) void finalize_kernel(
    const char* __restrict__ ws, float* __restrict__ out)
{
    const double* bce_partial = (const double*)(ws + WS_BCE);
    const float* var_partial = (const float*)(ws + WS_VAR);
    const float* avg_partial = (const float*)(ws + WS_AVG);
    __shared__ double sb[4];
    __shared__ float sv[4], sa[4];
    const int tid = threadIdx.x;

    double bsum = 0.0;
    for (int i = tid; i < NBLK_BCE; i += 256) bsum += bce_partial[i];

    float vsum = 0.0f;
    for (int p = tid; p < Zn * Zn; p += 256) {
        float v = 0.0f;
        #pragma unroll
        for (int m = 0; m < NMOM; ++m) v += var_partial[m * (Zn * Zn) + p];
        const int i = p / Zn, j = p - i * Zn;
        const float e = v * (1.0f / (float)Bn) - ((i == j) ? 1.0f : 0.0f);
        vsum += fabsf(e);
    }

    float asum = 0.0f;
    for (int z = tid; z < Zn; z += 256) {
        float a = 0.0f;
        #pragma unroll
        for (int m = 0; m < NMOM; ++m) a += avg_partial[m * Zn + z];
        asum += a * a;
    }

    #pragma unroll
    for (int o = 32; o; o >>= 1) {
        bsum += __shfl_xor(bsum, o);
        vsum += __shfl_xor(vsum, o);
        asum += __shfl_xor(asum, o);
    }
    if ((tid & 63) == 0) { const int w = tid >> 6; sb[w] = bsum; sv[w] = vsum; sa[w] = asum; }
    __syncthreads();
    if (tid == 0) {
        const double tb = (sb[0] + sb[1]) + (sb[2] + sb[3]);
        const double tv = (double)((sv[0] + sv[1]) + (sv[2] + sv[3]));
        const double ta = (double)((sa[0] + sa[1]) + (sa[2] + sa[3]));
        const double bce = -tb / ((double)Sn * (double)Bn);
        const double mom = ta / ((double)Bn * (double)Bn * (double)Zn)
                         + tv / ((double)Zn * (double)Zn);
        out[0] = (float)(bce + mom);
    }
}

extern "C" void kernel_launch(void* const* d_in, const int* in_sizes, int n_in,
                              void* d_out, int out_size, void* d_ws, size_t ws_size,
                              hipStream_t stream)
{
    const float* x     = (const float*)d_in[0];
    const float* recon = (const float*)d_in[1];
    const float* mu    = (const float*)d_in[2];
    // d_in[3] = log_var: unused by the reference
    const float* masks = (const float*)d_in[4];
    const int*   lhs   = (const int*)d_in[5];
    float* out = (float*)d_out;
    char* ws = (char*)d_ws;

    setup_kernel<<<1, 256, 0, stream>>>(masks, lhs, ws);
    main_kernel<<<NBLK_TOT, 256, 0, stream>>>(x, recon, mu, ws);
    finalize_kernel<<<1, 256, 0, stream>>>(ws, out);
}